// Round 1
// baseline (582.229 us; speedup 1.0000x reference)
//
#include <hip/hip_runtime.h>
#include <cstdint>
#include <cstddef>

constexpr int D = 256;       // embedding dim
constexpr int C = 128;       // num classes
constexpr float MARGIN = 1.0f;

// ---------------- K1: fp32 GEMM (emb @ W^T + b) fused with per-row top-2 ----------------
constexpr int BM = 128;      // rows per block
constexpr int BK = 32;       // k-tile
constexpr int PAD = 132;     // padded row stride (multiple of 4 for float4 alignment, +4 to spread banks)

__launch_bounds__(256)
__global__ void k1_logits_top2(const float* __restrict__ emb,
                               const int*   __restrict__ labels,
                               const float* __restrict__ W,
                               const float* __restrict__ bias,
                               int*         __restrict__ target_neg)
{
    union Sh {
        struct { float As[BK][PAD]; float Ws[BK][PAD]; } s;
        struct { float v[BM][16][2]; int id[BM][16][2]; } c;
    };
    __shared__ Sh sh;
    const int tid = threadIdx.x;
    const int tx = tid & 15;        // col group: cols tx*8 .. tx*8+7
    const int ty = tid >> 4;        // row group: rows ty*8 .. ty*8+7
    const long row0 = (long)blockIdx.x * BM;

    float acc[8][8];
#pragma unroll
    for (int i = 0; i < 8; ++i)
#pragma unroll
        for (int j = 0; j < 8; ++j) acc[i][j] = 0.0f;

    for (int k0 = 0; k0 < D; k0 += BK) {
        __syncthreads();
        // stage A: 128 rows x 32 k, transposed into As[k][row]
#pragma unroll
        for (int p = 0; p < 4; ++p) {
            int f = tid + 256 * p;          // 1024 float4 total
            int r = f >> 3, seg = f & 7;
            float4 v = *reinterpret_cast<const float4*>(&emb[(size_t)(row0 + r) * D + k0 + seg * 4]);
            sh.s.As[seg * 4 + 0][r] = v.x;
            sh.s.As[seg * 4 + 1][r] = v.y;
            sh.s.As[seg * 4 + 2][r] = v.z;
            sh.s.As[seg * 4 + 3][r] = v.w;
        }
        // stage W: 128 classes x 32 k, transposed into Ws[k][class]
#pragma unroll
        for (int p = 0; p < 4; ++p) {
            int f = tid + 256 * p;
            int r = f >> 3, seg = f & 7;
            float4 v = *reinterpret_cast<const float4*>(&W[(size_t)r * D + k0 + seg * 4]);
            sh.s.Ws[seg * 4 + 0][r] = v.x;
            sh.s.Ws[seg * 4 + 1][r] = v.y;
            sh.s.Ws[seg * 4 + 2][r] = v.z;
            sh.s.Ws[seg * 4 + 3][r] = v.w;
        }
        __syncthreads();
#pragma unroll
        for (int kk = 0; kk < BK; ++kk) {
            float a[8], b[8];
            *reinterpret_cast<float4*>(&a[0]) = *reinterpret_cast<const float4*>(&sh.s.As[kk][ty * 8]);
            *reinterpret_cast<float4*>(&a[4]) = *reinterpret_cast<const float4*>(&sh.s.As[kk][ty * 8 + 4]);
            *reinterpret_cast<float4*>(&b[0]) = *reinterpret_cast<const float4*>(&sh.s.Ws[kk][tx * 8]);
            *reinterpret_cast<float4*>(&b[4]) = *reinterpret_cast<const float4*>(&sh.s.Ws[kk][tx * 8 + 4]);
#pragma unroll
            for (int i = 0; i < 8; ++i)
#pragma unroll
                for (int j = 0; j < 8; ++j) acc[i][j] = fmaf(a[i], b[j], acc[i][j]);
        }
    }
    __syncthreads();

    float bv[8];
#pragma unroll
    for (int j = 0; j < 8; ++j) bv[j] = bias[tx * 8 + j];

    // per-thread top-2 over its 8 cols, per row (ties -> lower class index wins)
#pragma unroll
    for (int i = 0; i < 8; ++i) {
        float v1 = -3.4e38f, v2 = -3.4e38f;
        int i1 = -1, i2 = -1;
#pragma unroll
        for (int j = 0; j < 8; ++j) {
            float v = acc[i][j] + bv[j];
            int cc = tx * 8 + j;
            if (v > v1) { v2 = v1; i2 = i1; v1 = v; i1 = cc; }
            else if (v > v2) { v2 = v; i2 = cc; }
        }
        int r = ty * 8 + i;
        sh.c.v[r][tx][0] = v1; sh.c.v[r][tx][1] = v2;
        sh.c.id[r][tx][0] = i1; sh.c.id[r][tx][1] = i2;
    }
    __syncthreads();
    if (tid < BM) {
        int r = tid;
        float v1 = -3.4e38f, v2 = -3.4e38f;
        int i1 = -1, i2 = -1;
        for (int g = 0; g < 16; ++g) {   // groups in increasing class order -> stable ties
            float a1 = sh.c.v[r][g][0]; int c1 = sh.c.id[r][g][0];
            float a2 = sh.c.v[r][g][1]; int c2 = sh.c.id[r][g][1];
            if (a1 > v1) { v2 = v1; i2 = i1; v1 = a1; i1 = c1; }
            else if (a1 > v2) { v2 = a1; i2 = c1; }
            if (a2 > v1) { v2 = v1; i2 = i1; v1 = a2; i1 = c2; }
            else if (a2 > v2) { v2 = a2; i2 = c2; }
        }
        long gi = row0 + r;
        int lab = labels[gi];
        target_neg[gi] = (i1 == lab) ? i2 : i1;   // correct ? runner_up : predicted
    }
}

// ---------------- K2: per-64-chunk label histogram via wave match-mask ----------------
__global__ void k2_hist(const int* __restrict__ labels, int* __restrict__ hist, int nchunk)
{
    const int chunk = blockIdx.x;
    const int lane = threadIdx.x;
    const int i = chunk * 64 + lane;
    const int lab = labels[i];
    unsigned long long m = ~0ull;
#pragma unroll
    for (int b = 0; b < 7; ++b) {
        unsigned long long bal = __ballot((lab >> b) & 1);
        m &= ((lab >> b) & 1) ? bal : ~bal;
    }
    const int prefix = __popcll(m & ((1ull << lane) - 1ull));
    if (prefix == 0) hist[lab * nchunk + chunk] = __popcll(m);   // leader lane
}

// ---------------- K3: per-class exclusive scan over chunks (block per class) ----------------
__global__ void k3_scan(int* __restrict__ hist, int* __restrict__ counts, int nchunk)
{
    const int c = blockIdx.x;
    const int tid = threadIdx.x;
    const int per = nchunk / 256;           // 8 for B=131072
    const int base = c * nchunk + tid * per;
    int v[8];
    int s = 0;
#pragma unroll
    for (int j = 0; j < 8; ++j) {
        int x = (j < per) ? hist[base + j] : 0;
        v[j] = s; s += x;
    }
    __shared__ int sm[256];
    sm[tid] = s;
    __syncthreads();
    for (int off = 1; off < 256; off <<= 1) {
        int x = (tid >= off) ? sm[tid - off] : 0;
        __syncthreads();
        sm[tid] += x;
        __syncthreads();
    }
    const int excl = sm[tid] - s;
#pragma unroll
    for (int j = 0; j < 8; ++j)
        if (j < per) hist[base + j] = excl + v[j];
    if (tid == 255) counts[c] = sm[255];
}

// ---------------- K3b: class starts (exclusive scan over 128 counts) ----------------
__global__ void k3b_start(const int* __restrict__ counts, int* __restrict__ class_start)
{
    if (threadIdx.x == 0 && blockIdx.x == 0) {
        int s = 0;
        for (int c = 0; c < C; ++c) { class_start[c] = s; s += counts[c]; }
    }
}

// ---------------- K4: scatter stable order + rank ----------------
__global__ void k4_scatter(const int* __restrict__ labels, const int* __restrict__ hist,
                           const int* __restrict__ class_start,
                           int* __restrict__ order, int* __restrict__ rankArr, int nchunk)
{
    const int chunk = blockIdx.x;
    const int lane = threadIdx.x;
    const int i = chunk * 64 + lane;
    const int lab = labels[i];
    unsigned long long m = ~0ull;
#pragma unroll
    for (int b = 0; b < 7; ++b) {
        unsigned long long bal = __ballot((lab >> b) & 1);
        m &= ((lab >> b) & 1) ? bal : ~bal;
    }
    const int prefix = __popcll(m & ((1ull << lane) - 1ull));
    const int rank = hist[lab * nchunk + chunk] + prefix;
    order[class_start[lab] + rank] = i;
    rankArr[i] = rank;
}

// ---------------- K5a: sample pos/neg indices ----------------
__global__ void k5a_sample(const int* __restrict__ labels, const int* __restrict__ target_neg,
                           const int* __restrict__ counts, const int* __restrict__ class_start,
                           const int* __restrict__ order, const int* __restrict__ rankArr,
                           const int* __restrict__ r_pos, const int* __restrict__ r_neg,
                           int* __restrict__ pos_idx, int* __restrict__ neg_idx, int B)
{
    const int i = blockIdx.x * blockDim.x + threadIdx.x;
    if (i >= B) return;
    const int lab = labels[i];
    const int tn = target_neg[i];
    const int n_pos = counts[lab] - 1;
    const int n_neg = counts[tn];
    int pr = r_pos[i] % max(n_pos, 1);
    pr += (pr >= rankArr[i]) ? 1 : 0;
    int pidx_pos = class_start[lab] + pr; if (pidx_pos > B - 1) pidx_pos = B - 1;
    const int pidx = order[pidx_pos];
    int nr = r_neg[i] % max(n_neg, 1);
    int nidx_pos = class_start[tn] + nr; if (nidx_pos > B - 1) nidx_pos = B - 1;
    const int nidx = order[nidx_pos];
    const bool valid = (n_pos > 0) && (n_neg > 0);
    pos_idx[i] = valid ? pidx : -1;
    neg_idx[i] = nidx;
}

// ---------------- K5b: distances + hinge, wave per row ----------------
__launch_bounds__(256)
__global__ void k5b_dist(const float* __restrict__ emb,
                         const int* __restrict__ pos_idx, const int* __restrict__ neg_idx,
                         float* __restrict__ ploss, int* __restrict__ pcnt, int B)
{
    const int lane = threadIdx.x & 63;
    const int wid = threadIdx.x >> 6;
    const int wave = blockIdx.x * 4 + wid;
    const int nwaves = gridDim.x * 4;
    float lsum = 0.0f;
    int lcnt = 0;
    for (int row = wave; row < B; row += nwaves) {
        const int p = pos_idx[row];
        if (p >= 0) {
            const int n = neg_idx[row];
            const float4 a  = *reinterpret_cast<const float4*>(&emb[(size_t)row * D + lane * 4]);
            const float4 bp = *reinterpret_cast<const float4*>(&emb[(size_t)p   * D + lane * 4]);
            const float4 bn = *reinterpret_cast<const float4*>(&emb[(size_t)n   * D + lane * 4]);
            float dx, dp, dn;
            dx = a.x - bp.x; dp  = dx * dx;
            dx = a.y - bp.y; dp += dx * dx;
            dx = a.z - bp.z; dp += dx * dx;
            dx = a.w - bp.w; dp += dx * dx;
            dx = a.x - bn.x; dn  = dx * dx;
            dx = a.y - bn.y; dn += dx * dx;
            dx = a.z - bn.z; dn += dx * dx;
            dx = a.w - bn.w; dn += dx * dx;
#pragma unroll
            for (int off = 32; off >= 1; off >>= 1) {
                dp += __shfl_xor(dp, off);
                dn += __shfl_xor(dn, off);
            }
            float l = sqrtf(dp) - sqrtf(dn) + MARGIN;
            lsum += fmaxf(l, 0.0f);
            lcnt += 1;
        }
    }
    __shared__ float sl[4];
    __shared__ int   sc[4];
    if (lane == 0) { sl[wid] = lsum; sc[wid] = lcnt; }
    __syncthreads();
    if (threadIdx.x == 0) {
        ploss[blockIdx.x] = sl[0] + sl[1] + sl[2] + sl[3];
        pcnt[blockIdx.x]  = sc[0] + sc[1] + sc[2] + sc[3];
    }
}

// ---------------- K6: final reduce + divide ----------------
__global__ void k6_final(const float* __restrict__ ploss, const int* __restrict__ pcnt,
                         float* __restrict__ out, int nb)
{
    const int tid = threadIdx.x;
    float s = 0.0f; int c = 0;
    for (int j = tid; j < nb; j += 256) { s += ploss[j]; c += pcnt[j]; }
    __shared__ float sf[256];
    __shared__ int   si[256];
    sf[tid] = s; si[tid] = c;
    __syncthreads();
    for (int off = 128; off >= 1; off >>= 1) {
        if (tid < off) { sf[tid] += sf[tid + off]; si[tid] += si[tid + off]; }
        __syncthreads();
    }
    if (tid == 0) out[0] = sf[0] / (float)max(si[0], 1);
}

extern "C" void kernel_launch(void* const* d_in, const int* in_sizes, int n_in,
                              void* d_out, int out_size, void* d_ws, size_t ws_size,
                              hipStream_t stream) {
    const float* emb    = (const float*)d_in[0];
    const int*   labels = (const int*)d_in[1];
    const float* W      = (const float*)d_in[2];
    const float* bias   = (const float*)d_in[3];
    const int*   r_pos  = (const int*)d_in[4];
    const int*   r_neg  = (const int*)d_in[5];
    float* out = (float*)d_out;

    const int B = in_sizes[1];
    const int nchunk = B / 64;
    const int NB5 = 2048;

    size_t off = 0;
    auto alloc = [&](size_t bytes) -> void* {
        void* p = (char*)d_ws + off;
        off += (bytes + 255) & ~(size_t)255;
        return p;
    };
    int* hist        = (int*)alloc((size_t)C * nchunk * 4);
    int* counts      = (int*)alloc(C * 4);
    int* class_start = (int*)alloc(C * 4);
    int* target_neg  = (int*)alloc((size_t)B * 4);
    int* rankArr     = (int*)alloc((size_t)B * 4);
    int* order       = (int*)alloc((size_t)B * 4);
    int* pos_idx     = (int*)alloc((size_t)B * 4);
    int* neg_idx     = (int*)alloc((size_t)B * 4);
    float* ploss     = (float*)alloc((size_t)NB5 * 4);
    int* pcnt        = (int*)alloc((size_t)NB5 * 4);
    if (off > ws_size) return;   // insufficient workspace -> visible failure

    hipMemsetAsync(hist, 0, (size_t)C * nchunk * 4, stream);

    k1_logits_top2<<<B / BM, 256, 0, stream>>>(emb, labels, W, bias, target_neg);
    k2_hist<<<nchunk, 64, 0, stream>>>(labels, hist, nchunk);
    k3_scan<<<C, 256, 0, stream>>>(hist, counts, nchunk);
    k3b_start<<<1, 64, 0, stream>>>(counts, class_start);
    k4_scatter<<<nchunk, 64, 0, stream>>>(labels, hist, class_start, order, rankArr, nchunk);
    k5a_sample<<<(B + 255) / 256, 256, 0, stream>>>(labels, target_neg, counts, class_start,
                                                    order, rankArr, r_pos, r_neg,
                                                    pos_idx, neg_idx, B);
    k5b_dist<<<NB5, 256, 0, stream>>>(emb, pos_idx, neg_idx, ploss, pcnt, B);
    k6_final<<<1, 256, 0, stream>>>(ploss, pcnt, out, NB5);
}

// Round 2
// 300.615 us; speedup vs baseline: 1.9368x; 1.9368x over previous
//
#include <hip/hip_runtime.h>
#include <cstdint>
#include <cstddef>

constexpr int D = 256;       // embedding dim
constexpr int C = 128;       // num classes
constexpr float MARGIN = 1.0f;

typedef __attribute__((ext_vector_type(8))) short short8;
typedef __attribute__((ext_vector_type(4))) float f32x4;

// float -> bf16 bits (RNE)
__device__ inline unsigned f2bf_bits(float x) {
    unsigned u = __float_as_uint(x);
    return (u + 0x7FFFu + ((u >> 16) & 1u)) >> 16;
}

// split x into bf16 hi + bf16 lo (x ~= hi + lo to ~16 mantissa bits)
__device__ inline void cvt_split8(const float* xs, short8& h, short8& l) {
#pragma unroll
    for (int j = 0; j < 8; ++j) {
        float x = xs[j];
        unsigned hb = f2bf_bits(x);
        h[j] = (short)hb;
        float hf = __uint_as_float(hb << 16);
        unsigned lb = f2bf_bits(x - hf);
        l[j] = (short)lb;
    }
}

// ---------------- K0: convert W to bf16 hi/lo ----------------
__global__ void k0_convW(const float* __restrict__ W,
                         unsigned short* __restrict__ Whi,
                         unsigned short* __restrict__ Wlo)
{
    int i = blockIdx.x * 256 + threadIdx.x;     // 32768 total
    float x = W[i];
    unsigned hb = f2bf_bits(x);
    Whi[i] = (unsigned short)hb;
    float hf = __uint_as_float(hb << 16);
    Wlo[i] = (unsigned short)f2bf_bits(x - hf);
}

// ---------------- K1: split-bf16 MFMA logits + top-2 ----------------
// block = 512 thr (8 waves), 256 rows/block (32 rows/wave = 2 row-tiles)
// LDS: W hi/lo interleaved per class row: [n][hi 512B | lo 512B], XOR-swizzled.
__device__ __forceinline__ void merge_top2(float& v1, int& i1, float& v2, int& i2,
                                           float w1, int j1, float w2, int j2)
{
    bool b = (w1 > v1) || (w1 == v1 && j1 < i1);
    float best_v = b ? w1 : v1; int best_i = b ? j1 : i1;
    float lose_v = b ? v1 : w1; int lose_i = b ? i1 : j1;
    float sec_v  = b ? w2 : v2; int sec_i  = b ? j2 : i2;
    bool c = (lose_v > sec_v) || (lose_v == sec_v && lose_i < sec_i);
    v1 = best_v; i1 = best_i;
    v2 = c ? lose_v : sec_v; i2 = c ? lose_i : sec_i;
}

__launch_bounds__(512, 2)
__global__ void k1_logits_top2(const float* __restrict__ emb,
                               const int*   __restrict__ labels,
                               const unsigned short* __restrict__ Whi,
                               const unsigned short* __restrict__ Wlo,
                               const float* __restrict__ bias,
                               int*         __restrict__ target_neg)
{
    __shared__ uint4 ldsW4[8192];        // 128 KiB
    __shared__ float ldsBias[C];
    char* ldsW = (char*)ldsW4;
    const int tid = threadIdx.x;

    // stage W hi/lo into LDS, swizzled: 4096 16B chunks per array
    {
        const uint4* shi = (const uint4*)Whi;
        const uint4* slo = (const uint4*)Wlo;
#pragma unroll
        for (int c = tid; c < 4096; c += 512) {
            int n = c >> 5, slot = c & 31;                 // 32 chunks of 16B per class row
            int dst = (n * 1024 + slot * 16) ^ ((n & 7) << 4);
            *(uint4*)(ldsW + dst)       = shi[c];
            *(uint4*)(ldsW + dst + 512) = slo[c];
        }
        if (tid < C) ldsBias[tid] = bias[tid];
    }
    __syncthreads();

    const int wid = tid >> 6, lane = tid & 63;
    const int l15 = lane & 15, lq = lane >> 4;
    const long row0 = (long)blockIdx.x * 256 + wid * 32;

    f32x4 acc[2][8];
#pragma unroll
    for (int rt = 0; rt < 2; ++rt)
#pragma unroll
        for (int t = 0; t < 8; ++t) acc[rt][t] = (f32x4){0.f, 0.f, 0.f, 0.f};

    const float* e0 = emb + (size_t)(row0 + l15) * D + 8 * lq;   // row l15, k-base 8*lq
    const float* e1 = e0 + (size_t)16 * D;                        // row l15+16
    const int xm = (l15 & 7) << 4;                                // swizzle mask

#pragma unroll
    for (int s = 0; s < 8; ++s) {                                 // k-step: k0 = 32*s
        float x0[8], x1[8];
        *(float4*)&x0[0] = *(const float4*)(e0 + 32 * s);
        *(float4*)&x0[4] = *(const float4*)(e0 + 32 * s + 4);
        *(float4*)&x1[0] = *(const float4*)(e1 + 32 * s);
        *(float4*)&x1[4] = *(const float4*)(e1 + 32 * s + 4);
        short8 a0h, a0l, a1h, a1l;
        cvt_split8(x0, a0h, a0l);
        cvt_split8(x1, a1h, a1l);

#pragma unroll
        for (int t = 0; t < 8; ++t) {
            int raw = (16 * t + l15) * 1024 + 64 * s + 16 * lq;   // class row base + k*2
            int addr = raw ^ xm;
            short8 bh = *(const short8*)(ldsW + addr);
            short8 bl = *(const short8*)(ldsW + addr + 512);
            acc[0][t] = __builtin_amdgcn_mfma_f32_16x16x32_bf16(a0h, bh, acc[0][t], 0, 0, 0);
            acc[0][t] = __builtin_amdgcn_mfma_f32_16x16x32_bf16(a0l, bh, acc[0][t], 0, 0, 0);
            acc[0][t] = __builtin_amdgcn_mfma_f32_16x16x32_bf16(a0h, bl, acc[0][t], 0, 0, 0);
            acc[1][t] = __builtin_amdgcn_mfma_f32_16x16x32_bf16(a1h, bh, acc[1][t], 0, 0, 0);
            acc[1][t] = __builtin_amdgcn_mfma_f32_16x16x32_bf16(a1l, bh, acc[1][t], 0, 0, 0);
            acc[1][t] = __builtin_amdgcn_mfma_f32_16x16x32_bf16(a1h, bl, acc[1][t], 0, 0, 0);
        }
    }

    // epilogue: bias + per-row top-2
    float bv[8];
#pragma unroll
    for (int t = 0; t < 8; ++t) bv[t] = ldsBias[16 * t + l15];

    float v1[8], v2[8]; int i1[8], i2[8];   // slot = rt*4+reg; row = rt*16 + lq*4 + reg
#pragma unroll
    for (int rt = 0; rt < 2; ++rt)
#pragma unroll
        for (int reg = 0; reg < 4; ++reg) {
            int sIdx = rt * 4 + reg;
            float a1 = -3.4e38f, a2 = -3.4e38f; int c1 = -1, c2 = -1;
#pragma unroll
            for (int t = 0; t < 8; ++t) {
                float v = acc[rt][t][reg] + bv[t];
                int c = 16 * t + l15;
                if (v > a1) { a2 = a1; c2 = c1; a1 = v; c1 = c; }
                else if (v > a2) { a2 = v; c2 = c; }
            }
            v1[sIdx] = a1; i1[sIdx] = c1; v2[sIdx] = a2; i2[sIdx] = c2;
        }
#pragma unroll
    for (int step = 1; step <= 8; step <<= 1) {
#pragma unroll
        for (int sIdx = 0; sIdx < 8; ++sIdx) {
            float w1 = __shfl_xor(v1[sIdx], step);
            int   j1 = __shfl_xor(i1[sIdx], step);
            float w2 = __shfl_xor(v2[sIdx], step);
            int   j2 = __shfl_xor(i2[sIdx], step);
            merge_top2(v1[sIdx], i1[sIdx], v2[sIdx], i2[sIdx], w1, j1, w2, j2);
        }
    }
    if (l15 == 0) {
#pragma unroll
        for (int rt = 0; rt < 2; ++rt)
#pragma unroll
            for (int reg = 0; reg < 4; ++reg) {
                int sIdx = rt * 4 + reg;
                long grow = row0 + rt * 16 + lq * 4 + reg;
                int lab = labels[grow];
                target_neg[grow] = (i1[sIdx] == lab) ? i2[sIdx] : i1[sIdx];
            }
    }
}

// ---------------- K2: per-64-chunk label histogram via wave match-mask ----------------
__global__ void k2_hist(const int* __restrict__ labels, int* __restrict__ hist, int nchunk)
{
    const int chunk = blockIdx.x;
    const int lane = threadIdx.x;
    const int i = chunk * 64 + lane;
    const int lab = labels[i];
    unsigned long long m = ~0ull;
#pragma unroll
    for (int b = 0; b < 7; ++b) {
        unsigned long long bal = __ballot((lab >> b) & 1);
        m &= ((lab >> b) & 1) ? bal : ~bal;
    }
    const int prefix = __popcll(m & ((1ull << lane) - 1ull));
    if (prefix == 0) hist[lab * nchunk + chunk] = __popcll(m);   // leader lane
}

// ---------------- K3: per-class exclusive scan over chunks ----------------
__global__ void k3_scan(int* __restrict__ hist, int* __restrict__ counts, int nchunk)
{
    const int c = blockIdx.x;
    const int tid = threadIdx.x;
    const int per = nchunk / 256;           // 8 for B=131072
    const int base = c * nchunk + tid * per;
    int v[8];
    int s = 0;
#pragma unroll
    for (int j = 0; j < 8; ++j) {
        int x = (j < per) ? hist[base + j] : 0;
        v[j] = s; s += x;
    }
    __shared__ int sm[256];
    sm[tid] = s;
    __syncthreads();
    for (int off = 1; off < 256; off <<= 1) {
        int x = (tid >= off) ? sm[tid - off] : 0;
        __syncthreads();
        sm[tid] += x;
        __syncthreads();
    }
    const int excl = sm[tid] - s;
#pragma unroll
    for (int j = 0; j < 8; ++j)
        if (j < per) hist[base + j] = excl + v[j];
    if (tid == 255) counts[c] = sm[255];
}

// ---------------- K3b: class starts ----------------
__global__ void k3b_start(const int* __restrict__ counts, int* __restrict__ class_start)
{
    if (threadIdx.x == 0 && blockIdx.x == 0) {
        int s = 0;
        for (int c = 0; c < C; ++c) { class_start[c] = s; s += counts[c]; }
    }
}

// ---------------- K4: scatter stable order + rank ----------------
__global__ void k4_scatter(const int* __restrict__ labels, const int* __restrict__ hist,
                           const int* __restrict__ class_start,
                           int* __restrict__ order, int* __restrict__ rankArr, int nchunk)
{
    const int chunk = blockIdx.x;
    const int lane = threadIdx.x;
    const int i = chunk * 64 + lane;
    const int lab = labels[i];
    unsigned long long m = ~0ull;
#pragma unroll
    for (int b = 0; b < 7; ++b) {
        unsigned long long bal = __ballot((lab >> b) & 1);
        m &= ((lab >> b) & 1) ? bal : ~bal;
    }
    const int prefix = __popcll(m & ((1ull << lane) - 1ull));
    const int rank = hist[lab * nchunk + chunk] + prefix;
    order[class_start[lab] + rank] = i;
    rankArr[i] = rank;
}

// ---------------- K5a: sample pos/neg indices ----------------
__global__ void k5a_sample(const int* __restrict__ labels, const int* __restrict__ target_neg,
                           const int* __restrict__ counts, const int* __restrict__ class_start,
                           const int* __restrict__ order, const int* __restrict__ rankArr,
                           const int* __restrict__ r_pos, const int* __restrict__ r_neg,
                           int* __restrict__ pos_idx, int* __restrict__ neg_idx, int B)
{
    const int i = blockIdx.x * blockDim.x + threadIdx.x;
    if (i >= B) return;
    const int lab = labels[i];
    const int tn = target_neg[i];
    const int n_pos = counts[lab] - 1;
    const int n_neg = counts[tn];
    int pr = r_pos[i] % max(n_pos, 1);
    pr += (pr >= rankArr[i]) ? 1 : 0;
    int pidx_pos = class_start[lab] + pr; if (pidx_pos > B - 1) pidx_pos = B - 1;
    const int pidx = order[pidx_pos];
    int nr = r_neg[i] % max(n_neg, 1);
    int nidx_pos = class_start[tn] + nr; if (nidx_pos > B - 1) nidx_pos = B - 1;
    const int nidx = order[nidx_pos];
    const bool valid = (n_pos > 0) && (n_neg > 0);
    pos_idx[i] = valid ? pidx : -1;
    neg_idx[i] = nidx;
}

// ---------------- K5b: distances + hinge, 16 lanes per row ----------------
__launch_bounds__(256)
__global__ void k5b_dist(const float* __restrict__ emb,
                         const int* __restrict__ pos_idx, const int* __restrict__ neg_idx,
                         float* __restrict__ ploss, int* __restrict__ pcnt, int B)
{
    const int lane = threadIdx.x & 63;
    const int wid = threadIdx.x >> 6;
    const int l16 = threadIdx.x & 15;
    const int g = (blockIdx.x * blockDim.x + threadIdx.x) >> 4;
    const int ngroups = (gridDim.x * blockDim.x) >> 4;
    float lsum = 0.0f;
    int lcnt = 0;
    for (int row = g; row < B; row += ngroups) {
        const int p = pos_idx[row];
        if (p >= 0) {
            const int n = neg_idx[row];
            const float4* a4 = (const float4*)(emb + (size_t)row * D);
            const float4* p4 = (const float4*)(emb + (size_t)p   * D);
            const float4* n4 = (const float4*)(emb + (size_t)n   * D);
            float dp = 0.0f, dn = 0.0f;
#pragma unroll
            for (int j = 0; j < 4; ++j) {
                float4 a  = a4[l16 + 16 * j];
                float4 bp = p4[l16 + 16 * j];
                float4 bn = n4[l16 + 16 * j];
                float dx;
                dx = a.x - bp.x; dp = fmaf(dx, dx, dp);
                dx = a.y - bp.y; dp = fmaf(dx, dx, dp);
                dx = a.z - bp.z; dp = fmaf(dx, dx, dp);
                dx = a.w - bp.w; dp = fmaf(dx, dx, dp);
                dx = a.x - bn.x; dn = fmaf(dx, dx, dn);
                dx = a.y - bn.y; dn = fmaf(dx, dx, dn);
                dx = a.z - bn.z; dn = fmaf(dx, dx, dn);
                dx = a.w - bn.w; dn = fmaf(dx, dx, dn);
            }
#pragma unroll
            for (int off = 8; off >= 1; off >>= 1) {
                dp += __shfl_xor(dp, off);
                dn += __shfl_xor(dn, off);
            }
            if (l16 == 0) {
                float l = sqrtf(dp) - sqrtf(dn) + MARGIN;
                lsum += fmaxf(l, 0.0f);
                lcnt += 1;
            }
        }
    }
#pragma unroll
    for (int off = 32; off >= 1; off >>= 1) {
        lsum += __shfl_xor(lsum, off);
        lcnt += __shfl_xor(lcnt, off);
    }
    __shared__ float sl[4];
    __shared__ int   sc[4];
    if (lane == 0) { sl[wid] = lsum; sc[wid] = lcnt; }
    __syncthreads();
    if (threadIdx.x == 0) {
        ploss[blockIdx.x] = sl[0] + sl[1] + sl[2] + sl[3];
        pcnt[blockIdx.x]  = sc[0] + sc[1] + sc[2] + sc[3];
    }
}

// ---------------- K6: final reduce + divide ----------------
__global__ void k6_final(const float* __restrict__ ploss, const int* __restrict__ pcnt,
                         float* __restrict__ out, int nb)
{
    const int tid = threadIdx.x;
    float s = 0.0f; int c = 0;
    for (int j = tid; j < nb; j += 256) { s += ploss[j]; c += pcnt[j]; }
    __shared__ float sf[256];
    __shared__ int   si[256];
    sf[tid] = s; si[tid] = c;
    __syncthreads();
    for (int off = 128; off >= 1; off >>= 1) {
        if (tid < off) { sf[tid] += sf[tid + off]; si[tid] += si[tid + off]; }
        __syncthreads();
    }
    if (tid == 0) out[0] = sf[0] / (float)max(si[0], 1);
}

extern "C" void kernel_launch(void* const* d_in, const int* in_sizes, int n_in,
                              void* d_out, int out_size, void* d_ws, size_t ws_size,
                              hipStream_t stream) {
    const float* emb    = (const float*)d_in[0];
    const int*   labels = (const int*)d_in[1];
    const float* W      = (const float*)d_in[2];
    const float* bias   = (const float*)d_in[3];
    const int*   r_pos  = (const int*)d_in[4];
    const int*   r_neg  = (const int*)d_in[5];
    float* out = (float*)d_out;

    const int B = in_sizes[1];
    const int nchunk = B / 64;
    const int NB5 = 2048;

    size_t off = 0;
    auto alloc = [&](size_t bytes) -> void* {
        void* p = (char*)d_ws + off;
        off += (bytes + 255) & ~(size_t)255;
        return p;
    };
    int* hist        = (int*)alloc((size_t)C * nchunk * 4);
    int* counts      = (int*)alloc(C * 4);
    int* class_start = (int*)alloc(C * 4);
    int* target_neg  = (int*)alloc((size_t)B * 4);
    int* rankArr     = (int*)alloc((size_t)B * 4);
    int* order       = (int*)alloc((size_t)B * 4);
    int* pos_idx     = (int*)alloc((size_t)B * 4);
    int* neg_idx     = (int*)alloc((size_t)B * 4);
    float* ploss     = (float*)alloc((size_t)NB5 * 4);
    int* pcnt        = (int*)alloc((size_t)NB5 * 4);
    unsigned short* Whi = (unsigned short*)alloc((size_t)C * D * 2);
    unsigned short* Wlo = (unsigned short*)alloc((size_t)C * D * 2);
    if (off > ws_size) return;   // insufficient workspace -> visible failure

    hipMemsetAsync(hist, 0, (size_t)C * nchunk * 4, stream);

    k0_convW<<<(C * D) / 256, 256, 0, stream>>>(W, Whi, Wlo);
    k1_logits_top2<<<B / 256, 512, 0, stream>>>(emb, labels, Whi, Wlo, bias, target_neg);
    k2_hist<<<nchunk, 64, 0, stream>>>(labels, hist, nchunk);
    k3_scan<<<C, 256, 0, stream>>>(hist, counts, nchunk);
    k3b_start<<<1, 64, 0, stream>>>(counts, class_start);
    k4_scatter<<<nchunk, 64, 0, stream>>>(labels, hist, class_start, order, rankArr, nchunk);
    k5a_sample<<<(B + 255) / 256, 256, 0, stream>>>(labels, target_neg, counts, class_start,
                                                    order, rankArr, r_pos, r_neg,
                                                    pos_idx, neg_idx, B);
    k5b_dist<<<NB5, 256, 0, stream>>>(emb, pos_idx, neg_idx, ploss, pcnt, B);
    k6_final<<<1, 256, 0, stream>>>(ploss, pcnt, out, NB5);
}

// Round 3
// 286.938 us; speedup vs baseline: 2.0291x; 1.0477x over previous
//
#include <hip/hip_runtime.h>
#include <cstdint>
#include <cstddef>

constexpr int D = 256;       // embedding dim
constexpr int C = 128;       // num classes
constexpr float MARGIN = 1.0f;

typedef __attribute__((ext_vector_type(8))) short short8;
typedef __attribute__((ext_vector_type(4))) float f32x4;

// float -> bf16 bits (RNE)
__device__ inline unsigned f2bf(float x) {
    unsigned u = __float_as_uint(x);
    return (u + 0x7FFFu + ((u >> 16) & 1u)) >> 16;
}

// split x into bf16 hi + bf16 lo (x ~= hi + lo, exact to ~16 mantissa bits)
__device__ inline void cvt_split8(const float* xs, short8& h, short8& l) {
#pragma unroll
    for (int j = 0; j < 8; ++j) {
        float x = xs[j];
        unsigned hb = f2bf(x);
        h[j] = (short)hb;
        float hf = __uint_as_float(hb << 16);
        l[j] = (short)f2bf(x - hf);
    }
}

__device__ __forceinline__ void merge_top2(float& v1, int& i1, float& v2, int& i2,
                                           float w1, int j1, float w2, int j2)
{
    bool b = (w1 > v1) || (w1 == v1 && j1 < i1);
    float best_v = b ? w1 : v1; int best_i = b ? j1 : i1;
    float lose_v = b ? v1 : w1; int lose_i = b ? i1 : j1;
    float sec_v  = b ? w2 : v2; int sec_i  = b ? j2 : i2;
    bool c = (lose_v > sec_v) || (lose_v == sec_v && lose_i < sec_i);
    v1 = best_v; i1 = best_i;
    v2 = c ? lose_v : sec_v; i2 = c ? lose_i : sec_i;
}

// ---------------- K1: 2-term split-bf16 MFMA logits + top-2 + emb bf16 export ----------------
// block = 512 thr (8 waves), 256 rows/block. LDS: Whi only (64.5 KiB) -> 2 blocks/CU.
__launch_bounds__(512, 4)
__global__ void k1_logits_top2(const float* __restrict__ emb,
                               const int*   __restrict__ labels,
                               const float* __restrict__ W,
                               const float* __restrict__ bias,
                               int*         __restrict__ target_neg,
                               unsigned short* __restrict__ embh,   // may be null
                               int do_store)
{
    __shared__ char ldsW[C * 512];       // 64 KiB: 128 class rows x 256 bf16, swizzled
    __shared__ float ldsBias[C];
    const int tid = threadIdx.x;

    // stage + convert W (fp32 -> bf16 hi), XOR-swizzled 16B chunks
#pragma unroll
    for (int c = tid; c < 4096; c += 512) {
        int n = c >> 5, slot = c & 31;
        const float* src = W + n * 256 + slot * 8;
        float4 f0 = *(const float4*)src;
        float4 f1 = *(const float4*)(src + 4);
        short8 h;
        h[0] = (short)f2bf(f0.x); h[1] = (short)f2bf(f0.y);
        h[2] = (short)f2bf(f0.z); h[3] = (short)f2bf(f0.w);
        h[4] = (short)f2bf(f1.x); h[5] = (short)f2bf(f1.y);
        h[6] = (short)f2bf(f1.z); h[7] = (short)f2bf(f1.w);
        int dst = (n * 512 + slot * 16) ^ ((n & 7) << 4);
        *(short8*)(ldsW + dst) = h;
    }
    if (tid < C) ldsBias[tid] = bias[tid];
    __syncthreads();

    const int wid = tid >> 6, lane = tid & 63;
    const int l15 = lane & 15, lq = lane >> 4;
    const long row0 = (long)blockIdx.x * 256 + wid * 32;

    f32x4 acc[2][8];
#pragma unroll
    for (int rt = 0; rt < 2; ++rt)
#pragma unroll
        for (int t = 0; t < 8; ++t) acc[rt][t] = (f32x4){0.f, 0.f, 0.f, 0.f};

    const float* e0 = emb + (size_t)(row0 + l15) * D + 8 * lq;   // row l15, k-base 8*lq
    const float* e1 = e0 + (size_t)16 * D;                        // row l15+16
    char* eh0 = (char*)embh + (size_t)(row0 + l15) * 512 + 16 * lq;
    char* eh1 = eh0 + (size_t)16 * 512;
    const int xm = (l15 & 7) << 4;

#pragma unroll
    for (int s = 0; s < 8; ++s) {                                 // k-step: k0 = 32*s
        float x0[8], x1[8];
        *(float4*)&x0[0] = *(const float4*)(e0 + 32 * s);
        *(float4*)&x0[4] = *(const float4*)(e0 + 32 * s + 4);
        *(float4*)&x1[0] = *(const float4*)(e1 + 32 * s);
        *(float4*)&x1[4] = *(const float4*)(e1 + 32 * s + 4);
        short8 a0h, a0l, a1h, a1l;
        cvt_split8(x0, a0h, a0l);
        cvt_split8(x1, a1h, a1l);
        if (do_store) {
            *(short8*)(eh0 + 64 * s) = a0h;
            *(short8*)(eh1 + 64 * s) = a1h;
        }
#pragma unroll
        for (int t = 0; t < 8; ++t) {
            int addr = ((16 * t + l15) * 512 + 64 * s + 16 * lq) ^ xm;
            short8 bh = *(const short8*)(ldsW + addr);
            acc[0][t] = __builtin_amdgcn_mfma_f32_16x16x32_bf16(a0h, bh, acc[0][t], 0, 0, 0);
            acc[0][t] = __builtin_amdgcn_mfma_f32_16x16x32_bf16(a0l, bh, acc[0][t], 0, 0, 0);
            acc[1][t] = __builtin_amdgcn_mfma_f32_16x16x32_bf16(a1h, bh, acc[1][t], 0, 0, 0);
            acc[1][t] = __builtin_amdgcn_mfma_f32_16x16x32_bf16(a1l, bh, acc[1][t], 0, 0, 0);
        }
    }

    // epilogue: bias + per-row top-2 (col = class = 16t+l15; row = rt*16 + lq*4 + reg)
    float bv[8];
#pragma unroll
    for (int t = 0; t < 8; ++t) bv[t] = ldsBias[16 * t + l15];

    float v1[8], v2[8]; int i1[8], i2[8];
#pragma unroll
    for (int rt = 0; rt < 2; ++rt)
#pragma unroll
        for (int reg = 0; reg < 4; ++reg) {
            int sIdx = rt * 4 + reg;
            float a1 = -3.4e38f, a2 = -3.4e38f; int c1 = -1, c2 = -1;
#pragma unroll
            for (int t = 0; t < 8; ++t) {
                float v = acc[rt][t][reg] + bv[t];
                int c = 16 * t + l15;
                if (v > a1) { a2 = a1; c2 = c1; a1 = v; c1 = c; }
                else if (v > a2) { a2 = v; c2 = c; }
            }
            v1[sIdx] = a1; i1[sIdx] = c1; v2[sIdx] = a2; i2[sIdx] = c2;
        }
#pragma unroll
    for (int step = 1; step <= 8; step <<= 1) {
#pragma unroll
        for (int sIdx = 0; sIdx < 8; ++sIdx) {
            float w1 = __shfl_xor(v1[sIdx], step);
            int   j1 = __shfl_xor(i1[sIdx], step);
            float w2 = __shfl_xor(v2[sIdx], step);
            int   j2 = __shfl_xor(i2[sIdx], step);
            merge_top2(v1[sIdx], i1[sIdx], v2[sIdx], i2[sIdx], w1, j1, w2, j2);
        }
    }
    if (l15 == 0) {
#pragma unroll
        for (int rt = 0; rt < 2; ++rt)
#pragma unroll
            for (int reg = 0; reg < 4; ++reg) {
                int sIdx = rt * 4 + reg;
                long grow = row0 + rt * 16 + lq * 4 + reg;
                int lab = labels[grow];
                target_neg[grow] = (i1[sIdx] == lab) ? i2[sIdx] : i1[sIdx];
            }
    }
}

// ---------------- K2: per-64-chunk label histogram via wave match-mask ----------------
__global__ void k2_hist(const int* __restrict__ labels, int* __restrict__ hist, int nchunk)
{
    const int chunk = blockIdx.x * 4 + (threadIdx.x >> 6);
    const int lane = threadIdx.x & 63;
    const int i = chunk * 64 + lane;
    const int lab = labels[i];
    unsigned long long m = ~0ull;
#pragma unroll
    for (int b = 0; b < 7; ++b) {
        unsigned long long bal = __ballot((lab >> b) & 1);
        m &= ((lab >> b) & 1) ? bal : ~bal;
    }
    const int prefix = __popcll(m & ((1ull << lane) - 1ull));
    if (prefix == 0) hist[lab * nchunk + chunk] = __popcll(m);   // leader lane
}

// ---------------- K3: per-class exclusive scan over chunks ----------------
__global__ void k3_scan(int* __restrict__ hist, int* __restrict__ counts, int nchunk)
{
    const int c = blockIdx.x;
    const int tid = threadIdx.x;
    const int per = nchunk / 256;           // 8 for B=131072
    const int base = c * nchunk + tid * per;
    int v[8];
    int s = 0;
#pragma unroll
    for (int j = 0; j < 8; ++j) {
        int x = (j < per) ? hist[base + j] : 0;
        v[j] = s; s += x;
    }
    __shared__ int sm[256];
    sm[tid] = s;
    __syncthreads();
    for (int off = 1; off < 256; off <<= 1) {
        int x = (tid >= off) ? sm[tid - off] : 0;
        __syncthreads();
        sm[tid] += x;
        __syncthreads();
    }
    const int excl = sm[tid] - s;
#pragma unroll
    for (int j = 0; j < 8; ++j)
        if (j < per) hist[base + j] = excl + v[j];
    if (tid == 255) counts[c] = sm[255];
}

// ---------------- K3b: class starts ----------------
__global__ void k3b_start(const int* __restrict__ counts, int* __restrict__ class_start)
{
    if (threadIdx.x == 0 && blockIdx.x == 0) {
        int s = 0;
        for (int c = 0; c < C; ++c) { class_start[c] = s; s += counts[c]; }
    }
}

// ---------------- K4: scatter stable order + rank ----------------
__global__ void k4_scatter(const int* __restrict__ labels, const int* __restrict__ hist,
                           const int* __restrict__ class_start,
                           int* __restrict__ order, int* __restrict__ rankArr, int nchunk)
{
    const int chunk = blockIdx.x * 4 + (threadIdx.x >> 6);
    const int lane = threadIdx.x & 63;
    const int i = chunk * 64 + lane;
    const int lab = labels[i];
    unsigned long long m = ~0ull;
#pragma unroll
    for (int b = 0; b < 7; ++b) {
        unsigned long long bal = __ballot((lab >> b) & 1);
        m &= ((lab >> b) & 1) ? bal : ~bal;
    }
    const int prefix = __popcll(m & ((1ull << lane) - 1ull));
    const int rank = hist[lab * nchunk + chunk] + prefix;
    order[class_start[lab] + rank] = i;
    rankArr[i] = rank;
}

// ---------------- K56: fused sampling + distances + hinge ----------------
__device__ inline void acc_pair(unsigned a, unsigned b, float& s) {
    float d0 = __uint_as_float(a << 16)        - __uint_as_float(b << 16);
    float d1 = __uint_as_float(a & 0xFFFF0000u) - __uint_as_float(b & 0xFFFF0000u);
    s = fmaf(d0, d0, s);
    s = fmaf(d1, d1, s);
}
__device__ inline void acc16(uint4 a, uint4 b, float& s) {
    acc_pair(a.x, b.x, s); acc_pair(a.y, b.y, s);
    acc_pair(a.z, b.z, s); acc_pair(a.w, b.w, s);
}

__launch_bounds__(256)
__global__ void k56_dist(const unsigned short* __restrict__ embh,
                         const float* __restrict__ embf,
                         const int* __restrict__ labels, const int* __restrict__ target_neg,
                         const int* __restrict__ counts, const int* __restrict__ class_start,
                         const int* __restrict__ order, const int* __restrict__ rankArr,
                         const int* __restrict__ r_pos, const int* __restrict__ r_neg,
                         float* __restrict__ ploss, int* __restrict__ pcnt,
                         int B, int use_bf16)
{
    const int lane = threadIdx.x & 63;
    const int wid = threadIdx.x >> 6;
    const int l16 = threadIdx.x & 15;
    const int g = (blockIdx.x * blockDim.x + threadIdx.x) >> 4;
    const int ngroups = (gridDim.x * blockDim.x) >> 4;
    float lsum = 0.0f;
    int lcnt = 0;
    for (int row = g; row < B; row += ngroups) {
        const int lab = labels[row];
        const int tn = target_neg[row];
        const int n_pos = counts[lab] - 1;
        const int n_neg = counts[tn];
        if (n_pos > 0 && n_neg > 0) {
            int pr = r_pos[row] % n_pos;
            pr += (pr >= rankArr[row]) ? 1 : 0;
            const int p = order[class_start[lab] + pr];
            const int nr = r_neg[row] % n_neg;
            const int n = order[class_start[tn] + nr];
            float dp = 0.0f, dn = 0.0f;
            if (use_bf16) {
                const uint4* a4 = (const uint4*)(embh + (size_t)row * D);
                const uint4* p4 = (const uint4*)(embh + (size_t)p   * D);
                const uint4* n4 = (const uint4*)(embh + (size_t)n   * D);
                uint4 av0 = a4[2 * l16], av1 = a4[2 * l16 + 1];
                uint4 pv0 = p4[2 * l16], pv1 = p4[2 * l16 + 1];
                uint4 nv0 = n4[2 * l16], nv1 = n4[2 * l16 + 1];
                acc16(av0, pv0, dp); acc16(av1, pv1, dp);
                acc16(av0, nv0, dn); acc16(av1, nv1, dn);
            } else {
                const float4* a4 = (const float4*)(embf + (size_t)row * D);
                const float4* p4 = (const float4*)(embf + (size_t)p   * D);
                const float4* n4 = (const float4*)(embf + (size_t)n   * D);
#pragma unroll
                for (int j = 0; j < 4; ++j) {
                    float4 a  = a4[l16 + 16 * j];
                    float4 bp = p4[l16 + 16 * j];
                    float4 bn = n4[l16 + 16 * j];
                    float dx;
                    dx = a.x - bp.x; dp = fmaf(dx, dx, dp);
                    dx = a.y - bp.y; dp = fmaf(dx, dx, dp);
                    dx = a.z - bp.z; dp = fmaf(dx, dx, dp);
                    dx = a.w - bp.w; dp = fmaf(dx, dx, dp);
                    dx = a.x - bn.x; dn = fmaf(dx, dx, dn);
                    dx = a.y - bn.y; dn = fmaf(dx, dx, dn);
                    dx = a.z - bn.z; dn = fmaf(dx, dx, dn);
                    dx = a.w - bn.w; dn = fmaf(dx, dx, dn);
                }
            }
#pragma unroll
            for (int off = 8; off >= 1; off >>= 1) {
                dp += __shfl_xor(dp, off);
                dn += __shfl_xor(dn, off);
            }
            if (l16 == 0) {
                float l = sqrtf(dp) - sqrtf(dn) + MARGIN;
                lsum += fmaxf(l, 0.0f);
                lcnt += 1;
            }
        }
    }
    // gather the 4 group leaders of each wave into lane 0
    lsum += __shfl_xor(lsum, 16); lcnt += __shfl_xor(lcnt, 16);
    lsum += __shfl_xor(lsum, 32); lcnt += __shfl_xor(lcnt, 32);
    __shared__ float sl[4];
    __shared__ int   sc[4];
    if (lane == 0) { sl[wid] = lsum; sc[wid] = lcnt; }
    __syncthreads();
    if (threadIdx.x == 0) {
        ploss[blockIdx.x] = sl[0] + sl[1] + sl[2] + sl[3];
        pcnt[blockIdx.x]  = sc[0] + sc[1] + sc[2] + sc[3];
    }
}

// ---------------- K6: final reduce + divide ----------------
__global__ void k6_final(const float* __restrict__ ploss, const int* __restrict__ pcnt,
                         float* __restrict__ out, int nb)
{
    const int tid = threadIdx.x;
    float s = 0.0f; int c = 0;
    for (int j = tid; j < nb; j += 256) { s += ploss[j]; c += pcnt[j]; }
    __shared__ float sf[256];
    __shared__ int   si[256];
    sf[tid] = s; si[tid] = c;
    __syncthreads();
    for (int off = 128; off >= 1; off >>= 1) {
        if (tid < off) { sf[tid] += sf[tid + off]; si[tid] += si[tid + off]; }
        __syncthreads();
    }
    if (tid == 0) out[0] = sf[0] / (float)max(si[0], 1);
}

extern "C" void kernel_launch(void* const* d_in, const int* in_sizes, int n_in,
                              void* d_out, int out_size, void* d_ws, size_t ws_size,
                              hipStream_t stream) {
    const float* emb    = (const float*)d_in[0];
    const int*   labels = (const int*)d_in[1];
    const float* W      = (const float*)d_in[2];
    const float* bias   = (const float*)d_in[3];
    const int*   r_pos  = (const int*)d_in[4];
    const int*   r_neg  = (const int*)d_in[5];
    float* out = (float*)d_out;

    const int B = in_sizes[1];
    const int nchunk = B / 64;
    const int NB5 = 2048;

    size_t off = 0;
    auto alloc = [&](size_t bytes) -> void* {
        void* p = (char*)d_ws + off;
        off += (bytes + 255) & ~(size_t)255;
        return p;
    };
    int* hist        = (int*)alloc((size_t)C * nchunk * 4);
    int* counts      = (int*)alloc(C * 4);
    int* class_start = (int*)alloc(C * 4);
    int* target_neg  = (int*)alloc((size_t)B * 4);
    int* rankArr     = (int*)alloc((size_t)B * 4);
    int* order       = (int*)alloc((size_t)B * 4);
    float* ploss     = (float*)alloc((size_t)NB5 * 4);
    int* pcnt        = (int*)alloc((size_t)NB5 * 4);
    if (off > ws_size) return;   // core scratch missing -> visible failure

    // optional bf16 emb mirror (large); fall back to fp32 distances if ws too small
    unsigned short* embh = (unsigned short*)alloc((size_t)B * D * 2);
    const int use_bf16 = (off <= ws_size) ? 1 : 0;

    hipMemsetAsync(hist, 0, (size_t)C * nchunk * 4, stream);

    k1_logits_top2<<<B / 256, 512, 0, stream>>>(emb, labels, W, bias, target_neg,
                                                use_bf16 ? embh : (unsigned short*)target_neg,
                                                use_bf16);
    k2_hist<<<nchunk / 4, 256, 0, stream>>>(labels, hist, nchunk);
    k3_scan<<<C, 256, 0, stream>>>(hist, counts, nchunk);
    k3b_start<<<1, 64, 0, stream>>>(counts, class_start);
    k4_scatter<<<nchunk / 4, 256, 0, stream>>>(labels, hist, class_start, order, rankArr, nchunk);
    k56_dist<<<NB5, 256, 0, stream>>>(embh, emb, labels, target_neg, counts, class_start,
                                      order, rankArr, r_pos, r_neg, ploss, pcnt, B, use_bf16);
    k6_final<<<1, 256, 0, stream>>>(ploss, pcnt, out, NB5);
}